// Round 11
// baseline (412.350 us; speedup 1.0000x reference)
//
#include <hip/hip_runtime.h>

// ---------------------------------------------------------------------------
// TextGCN (2-layer GCN, eval mode) on MI355X.
// Fusions:
//   * xw1_word = word @ (W_lin@W1) + (b_lin@W1)  (never materialize [N,768] x)
//   * layer 2: agg(h1@W2)[mask] == agg(h1)[mask] @ W2
// CSR holds RAW weights at build; degdis computes dis; prenorm folds dis[src]
// into entries.y. Self-loop has reserved slot offs[i] (no atomic).
// xw1/h1 bf16 in PERMUTED column order pi(pos)=(pos&3)*16+(pos>>2).
// k_main GEMMs are LDS-staged: 64-row blocks, double-buffered A-tile filled
// via global_load_lds (16B/lane), XOR-chunk swizzle for bank-free ds_reads,
// one barrier per k0. Word K=300: 9 staged k0 + direct tail.
// k_pre = fuseGEMM(epilogue also emits packWf) || packW1 || packW2 || cnt.
// scan_final computes its block base by reducing bsum inline (no scan_small).
// ---------------------------------------------------------------------------

typedef __attribute__((ext_vector_type(8))) short short8;   // 8 bf16 = 4 VGPR
typedef __attribute__((ext_vector_type(4))) float float4v;  // MFMA C/D frag

#define AS1 __attribute__((address_space(1)))
#define AS3 __attribute__((address_space(3)))

__device__ __forceinline__ unsigned short f2bf(float f) {   // RNE f32->bf16
  unsigned u = __float_as_uint(f);
  return (unsigned short)((u + 0x7FFFu + ((u >> 16) & 1u)) >> 16);
}
__device__ __forceinline__ float bf2f(unsigned short u) {
  return __uint_as_float((unsigned)u << 16);
}
__device__ __forceinline__ int permcol(int p) {   // pi: pos -> true col
  return ((p & 3) << 4) | (p >> 2);
}

// pack W[K,64] fp32 -> bf16 fragment order: pack[((g*nk0+k0)*64+lane)*8+j]
// holds W[ksrc][(lane&15)+16g], ksrc = PERM ? pi(k) : k; zero past K.
template <bool PERM>
__device__ __forceinline__ void pack_w_body(const float* __restrict__ W, int K,
                                            int nk0, unsigned short* __restrict__ pack,
                                            int tid) {
  int lane = tid & 63;
  int rest = tid >> 6;
  int k0 = rest % nk0;
  int g = rest / nk0;
  int quad = lane >> 4;
  int n = (lane & 15) + g * 16;
  short8 v;
#pragma unroll
  for (int j = 0; j < 8; ++j) {
    int k = k0 * 32 + quad * 8 + j;
    int ks = PERM ? permcol(k) : k;
    float w = (k < K) ? W[(size_t)ks * 64 + n] : 0.f;
    v[j] = (short)f2bf(w);
  }
  *(short8*)(pack + (((size_t)(g * nk0 + k0) * 64 + lane) << 3)) = v;
}

// Register-path MFMA GEMM (fuse + final). RS rowsets share B loads.
// PACKOUT: fuse epilogue also scatters bf16 into packOut (nk0out=10 layout).
template <bool LAST, bool PACKED, int RS, bool PACKOUT>
__device__ __forceinline__ void mfma_gemm_body(
    const float* __restrict__ X, int ldx, const float* __restrict__ lastRow,
    const unsigned short* __restrict__ Wpack, const float* __restrict__ Wf,
    int nk0, int K, const float* __restrict__ bias,
    float* __restrict__ outv, int R, int waveIdx,
    unsigned short* __restrict__ packOut) {
  int r0 = waveIdx * 16 * RS;
  if (r0 >= R) return;
  const int lane = threadIdx.x & 63;
  const int quad = lane >> 4;
  const int m = lane & 15;
  const float* xrow[RS];
#pragma unroll
  for (int rs = 0; rs < RS; ++rs) {
    int row = r0 + rs * 16 + m;
    xrow[rs] = nullptr;
    if (row < R) xrow[rs] = (LAST && row == R - 1) ? lastRow : X + (size_t)row * ldx;
  }

  float4v acc[RS][4];
#pragma unroll
  for (int rs = 0; rs < RS; ++rs)
#pragma unroll
    for (int g = 0; g < 4; ++g) acc[rs][g] = (float4v){0.f, 0.f, 0.f, 0.f};

  for (int k0 = 0; k0 < nk0; ++k0) {
    int kb = k0 * 32 + quad * 8;
    float a[RS][8];
#pragma unroll
    for (int rs = 0; rs < RS; ++rs) {
      if (xrow[rs] && kb + 8 <= K) {
        float4 v0 = *(const float4*)(xrow[rs] + kb);
        float4 v1 = *(const float4*)(xrow[rs] + kb + 4);
        a[rs][0] = v0.x; a[rs][1] = v0.y; a[rs][2] = v0.z; a[rs][3] = v0.w;
        a[rs][4] = v1.x; a[rs][5] = v1.y; a[rs][6] = v1.z; a[rs][7] = v1.w;
      } else {
#pragma unroll
        for (int j = 0; j < 8; ++j) {
          int k = kb + j;
          a[rs][j] = (xrow[rs] && k < K) ? xrow[rs][k] : 0.f;
        }
      }
    }
    short8 bf[4];
#pragma unroll
    for (int g = 0; g < 4; ++g) {
      if (PACKED) {
        bf[g] = *(const short8*)(Wpack + (((size_t)(g * nk0 + k0) * 64 + lane) << 3));
      } else {
        int n = g * 16 + m;
#pragma unroll
        for (int j = 0; j < 8; ++j) {
          int k = kb + j;
          float w = (k < K) ? Wf[(size_t)k * 64 + n] : 0.f;
          bf[g][j] = (short)f2bf(w);
        }
      }
    }
#pragma unroll
    for (int rs = 0; rs < RS; ++rs) {
      short8 af;
#pragma unroll
      for (int j = 0; j < 8; ++j) af[j] = (short)f2bf(a[rs][j]);
#pragma unroll
      for (int g = 0; g < 4; ++g)
        acc[rs][g] = __builtin_amdgcn_mfma_f32_16x16x32_bf16(af, bf[g], acc[rs][g], 0, 0, 0);
    }
  }

#pragma unroll
  for (int rs = 0; rs < RS; ++rs) {
    int rb = r0 + rs * 16;
#pragma unroll
    for (int g = 0; g < 4; ++g) {
      float b = bias ? bias[g * 16 + m] : 0.f;
#pragma unroll
      for (int reg = 0; reg < 4; ++reg) {
        int r = rb + quad * 4 + reg;   // C/D: col=lane&15, row=quad*4+reg
        if (r < R) {
          float o = acc[rs][g][reg] + b;
          outv[(size_t)r * 64 + g * 16 + m] = o;
          if (PACKOUT && r < 300) {    // scatter into word-GEMM B-frag layout
            int k0p = r >> 5, quadp = (r >> 3) & 3, jp = r & 7;
            int lanep = quadp * 16 + m;
            packOut[(((size_t)(g * 10 + k0p) * 64 + lanep) << 3) + jp] = f2bf(o);
          }
        }
      }
    }
  }
}

// LDS-staged MFMA GEMM: 64 rows/block, 4 waves (16 rows each), double-buffered
// A-tile via global_load_lds, XOR-chunk swizzle, bf16-permuted output.
__device__ __forceinline__ void mfma_gemm_lds(
    const float* __restrict__ X, int ldx, int K, int nk0full, bool tail,
    const unsigned short* __restrict__ Wpack, int nk0,
    const float* __restrict__ bias,
    unsigned short* __restrict__ outv, int R, int row0, float* As) {
  const int t = threadIdx.x;
  const int wv = t >> 6;
  const int lane = t & 63;
  const int quad = lane >> 4;
  const int m = lane & 15;

  // staging: lane covers row h*32+wv*8+(lane>>3), LDS chunk lane&7 of that row;
  // chunk holds global chunk gc = ((lane&7)-(lane>>3))&7  (XOR/rot swizzle).
  int srow[2];
#pragma unroll
  for (int h = 0; h < 2; ++h) {
    int rg = row0 + h * 32 + wv * 8 + (lane >> 3);
    srow[h] = (rg < R) ? rg : (R - 1);
  }
  const int scol = ((((lane & 7) - (lane >> 3)) & 7)) << 2;
  const int ldsbase = (wv * 8) * 32;   // floats

  float4v acc[4];
#pragma unroll
  for (int g = 0; g < 4; ++g) acc[g] = (float4v){0.f, 0.f, 0.f, 0.f};

  auto stage = [&](int buf, int k0) {
    int kb = k0 << 5;
#pragma unroll
    for (int h = 0; h < 2; ++h) {
      const float* src = X + (size_t)srow[h] * ldx + kb + scol;
      __builtin_amdgcn_global_load_lds(
          (const AS1 void*)src,
          (AS3 void*)(As + buf * 2048 + h * 1024 + ldsbase), 16, 0, 0);
    }
  };

  const int r7 = m & 7;                          // (wv*16+m) & 7
  const float* rowb0 = As + ((wv * 16 + m) << 5);
  const int c0 = ((2 * quad + r7) & 7) << 2;     // LDS chunk of global chunk 2q
  const int c1 = ((2 * quad + 1 + r7) & 7) << 2; // LDS chunk of global chunk 2q+1

  auto computeK = [&](int buf, int k0) {
    const float* rb = rowb0 + buf * 2048;
    float4 v0 = *(const float4*)(rb + c0);
    float4 v1 = *(const float4*)(rb + c1);
    short8 af;
    af[0] = (short)f2bf(v0.x); af[1] = (short)f2bf(v0.y);
    af[2] = (short)f2bf(v0.z); af[3] = (short)f2bf(v0.w);
    af[4] = (short)f2bf(v1.x); af[5] = (short)f2bf(v1.y);
    af[6] = (short)f2bf(v1.z); af[7] = (short)f2bf(v1.w);
#pragma unroll
    for (int g = 0; g < 4; ++g) {
      short8 bf = *(const short8*)(Wpack + (((size_t)(g * nk0 + k0) * 64 + lane) << 3));
      acc[g] = __builtin_amdgcn_mfma_f32_16x16x32_bf16(af, bf, acc[g], 0, 0, 0);
    }
  };

  stage(0, 0);
  __syncthreads();
  for (int k0 = 0; k0 < nk0full; ++k0) {
    int buf = k0 & 1;
    if (k0 + 1 < nk0full) stage(buf ^ 1, k0 + 1);
    computeK(buf, k0);
    __syncthreads();
  }

  if (tail) {                                    // word: kb=288, cols 288..299
    int kb = nk0full << 5;
    int rg = row0 + wv * 16 + m;
    const float* xr = X + (size_t)((rg < R) ? rg : (R - 1)) * ldx;
    float a[8];
#pragma unroll
    for (int j = 0; j < 8; ++j) {
      int k = kb + (quad << 3) + j;
      a[j] = (k < K) ? xr[k] : 0.f;
    }
    short8 af;
#pragma unroll
    for (int j = 0; j < 8; ++j) af[j] = (short)f2bf(a[j]);
#pragma unroll
    for (int g = 0; g < 4; ++g) {
      short8 bf = *(const short8*)(Wpack + (((size_t)(g * nk0 + nk0full) * 64 + lane) << 3));
      acc[g] = __builtin_amdgcn_mfma_f32_16x16x32_bf16(af, bf, acc[g], 0, 0, 0);
    }
  }

  // epilogue: permuted bf16, lane m packs cols {m,16+m,32+m,48+m} as 8B
  float b0 = bias ? bias[m] : 0.f;
  float b1 = bias ? bias[16 + m] : 0.f;
  float b2 = bias ? bias[32 + m] : 0.f;
  float b3 = bias ? bias[48 + m] : 0.f;
  int rb = row0 + wv * 16;
#pragma unroll
  for (int j = 0; j < 4; ++j) {
    int r = rb + quad * 4 + j;
    if (r < R) {
      ushort4 pk;
      pk.x = f2bf(acc[0][j] + b0);
      pk.y = f2bf(acc[1][j] + b1);
      pk.z = f2bf(acc[2][j] + b2);
      pk.w = f2bf(acc[3][j] + b3);
      *(ushort4*)(outv + ((size_t)r * 64 + m * 4)) = pk;
    }
  }
}

// k_pre: fuse GEMM (emits WfuseB fp32 + packWf bf16) || packW1 || packW2 || cnt
__global__ __launch_bounds__(256) void k_pre(
    const float* __restrict__ Wlin, const float* __restrict__ blin,
    const float* __restrict__ W1, float* __restrict__ WfuseB,
    unsigned short* __restrict__ packWf, unsigned short* __restrict__ packW1,
    const float* __restrict__ W2, unsigned short* __restrict__ packW2,
    const int* __restrict__ ei, int E, int* __restrict__ cnt, int fuseBlocks) {
  int b = blockIdx.x;
  if (b < fuseBlocks) {
    mfma_gemm_body<true, false, 2, true>(Wlin, 768, blin, nullptr, W1, 24, 768,
                                         nullptr, WfuseB, 301,
                                         b * 4 + (threadIdx.x >> 6), packWf);
    return;
  }
  b -= fuseBlocks;
  if (b < 24) { pack_w_body<false>(W1, 768, 24, packW1, b * 256 + threadIdx.x); return; }
  b -= 24;
  if (b < 2) { pack_w_body<true>(W2, 64, 2, packW2, b * 256 + threadIdx.x); return; }
  b -= 2;
  int e0 = (b * 256 + threadIdx.x) * 4;
#pragma unroll
  for (int j = 0; j < 4; ++j) {
    int e = e0 + j;
    if (e < E) atomicAdd(cnt + ei[E + e], 1);   // fire-and-forget
  }
}

// k_main: doc MFMA (packed W1) || word MFMA (packWf), both LDS-staged
__global__ __launch_bounds__(256) void k_main(
    const float* __restrict__ doc, const unsigned short* __restrict__ packW1,
    unsigned short* __restrict__ xw1, int ND, int docBlocks,
    const float* __restrict__ wordf, const unsigned short* __restrict__ packWf,
    const float* __restrict__ bfuse, unsigned short* __restrict__ xw1word, int NW) {
  __shared__ float As[2][2048];
  int b = blockIdx.x;
  if (b < docBlocks) {
    mfma_gemm_lds(doc, 768, 768, 24, false, packW1, 24, nullptr,
                  xw1, ND, b * 64, &As[0][0]);
  } else {
    b -= docBlocks;
    mfma_gemm_lds(wordf, 300, 300, 9, true, packWf, 10, bfuse,
                  xw1word, NW, b * 64, &As[0][0]);
  }
}

// ---- scan: reduce pass -> per-block sums; final pass derives its base by
// reducing bsum[0..b) inline (no middle dispatch), writes offs/cursor/selfloop.
__global__ void k_scan_reduce(const int* __restrict__ cnt, int N, int* __restrict__ bsum) {
  __shared__ int sd[256];
  int b = blockIdx.x, t = threadIdx.x;
  int base = b * 1024 + t * 4;
  int s = 0;
#pragma unroll
  for (int j = 0; j < 4; ++j) s += (base + j < N) ? cnt[base + j] + 1 : 0;
  sd[t] = s; __syncthreads();
  for (int off = 128; off > 0; off >>= 1) {
    if (t < off) sd[t] += sd[t + off];
    __syncthreads();
  }
  if (t == 0) bsum[b] = sd[0];
}

__global__ void k_scan_final(const int* __restrict__ cnt, int N, const int* __restrict__ bsum,
                             int nb, int* __restrict__ offs, int* __restrict__ cursor,
                             int2* __restrict__ entries) {
  __shared__ int sd[256];
  int b = blockIdx.x, t = threadIdx.x;
  sd[t] = (t < b && t < nb) ? bsum[t] : 0;    // base = sum bsum[0..b)
  __syncthreads();
  for (int off = 128; off > 0; off >>= 1) {
    if (t < off) sd[t] += sd[t + off];
    __syncthreads();
  }
  int base = sd[0];
  __syncthreads();
  int bi = b * 1024 + t * 4;
  int v[4], loc = 0;
#pragma unroll
  for (int j = 0; j < 4; ++j) { v[j] = (bi + j < N) ? cnt[bi + j] + 1 : 0; loc += v[j]; }
  sd[t] = loc; __syncthreads();
  for (int off = 1; off < 256; off <<= 1) {
    int x = (t >= off) ? sd[t - off] : 0;
    __syncthreads();
    sd[t] += x;
    __syncthreads();
  }
  int run = base + sd[t] - loc;
#pragma unroll
  for (int j = 0; j < 4; ++j) {
    if (bi + j < N) {
      int i = bi + j;
      offs[i] = run;
      cursor[i] = run + 1;                               // slot 0 = self loop
      entries[run] = make_int2(i, __float_as_int(1.0f)); // raw w=1
      run += v[j];
    }
  }
  if (b == gridDim.x - 1 && t == 255) offs[N] = run;  // total = N + E
}

// CSR fill (4 edges/thread, 4 independent atomic chains)
__global__ __launch_bounds__(256) void k_fill(
    const int* __restrict__ ei, const float* __restrict__ ew, int E,
    int* __restrict__ cursor, int2* __restrict__ entries) {
  int e0 = (blockIdx.x * 256 + threadIdx.x) * 4;
  int src[4], dst[4];
  float w[4];
#pragma unroll
  for (int j = 0; j < 4; ++j) {
    int e = e0 + j;
    if (e < E) { src[j] = ei[e]; dst[j] = ei[E + e]; w[j] = ew[e]; }
  }
  int pos[4];
#pragma unroll
  for (int j = 0; j < 4; ++j)
    if (e0 + j < E) pos[j] = atomicAdd(cursor + dst[j], 1);
#pragma unroll
  for (int j = 0; j < 4; ++j)
    if (e0 + j < E) entries[pos[j]] = make_int2(src[j], __float_as_int(w[j]));
}

// deg->dis: segmented sum of RAW weights over CSR rows (atomic-free)
__global__ void k_degdis(const int2* __restrict__ entries, const int* __restrict__ offs,
                         float* __restrict__ dis, int N) {
  int i = blockIdx.x * blockDim.x + threadIdx.x;
  if (i >= N) return;
  int p = offs[i], pe = offs[i + 1];
  float d = 0.f;
  for (; p < pe; ++p) d += __int_as_float(entries[p].y);
  dis[i] = d > 0.f ? rsqrtf(fmaxf(d, 1e-12f)) : 0.f;
}

// fold dis[src] into entries.y (sequential r/m/w, coalesced)
__global__ void k_prenorm(int2* __restrict__ entries, const float* __restrict__ dis, int NE) {
  int p = blockIdx.x * blockDim.x + threadIdx.x;
  if (p >= NE) return;
  int2 e = entries[p];
  entries[p].y = __float_as_int(__int_as_float(e.y) * dis[e.x]);
}

// half-wave gather-accumulate: 32 lanes, each lane covers 2 cols (ushort2).
__device__ __forceinline__ void row_gather2(const unsigned short* __restrict__ xin,
                                            const int2* __restrict__ entries,
                                            int p, int pe, int l32,
                                            float& ra0, float& ra1) {
  float a0 = 0.f, a1 = 0.f;
  for (; p + 8 <= pe; p += 8) {
    int2 e[8];
#pragma unroll
    for (int j = 0; j < 8; ++j) e[j] = entries[p + j];
    unsigned x[8];
#pragma unroll
    for (int j = 0; j < 8; ++j)
      x[j] = *(const unsigned*)(xin + ((size_t)e[j].x << 6) + (l32 << 1));
#pragma unroll
    for (int j = 0; j < 8; ++j) {
      float w = __int_as_float(e[j].y);
      a0 = fmaf(bf2f((unsigned short)(x[j] & 0xffffu)), w, a0);
      a1 = fmaf(bf2f((unsigned short)(x[j] >> 16)), w, a1);
    }
  }
  if (p + 4 <= pe) {
    int2 e[4];
#pragma unroll
    for (int j = 0; j < 4; ++j) e[j] = entries[p + j];
    unsigned x[4];
#pragma unroll
    for (int j = 0; j < 4; ++j)
      x[j] = *(const unsigned*)(xin + ((size_t)e[j].x << 6) + (l32 << 1));
#pragma unroll
    for (int j = 0; j < 4; ++j) {
      float w = __int_as_float(e[j].y);
      a0 = fmaf(bf2f((unsigned short)(x[j] & 0xffffu)), w, a0);
      a1 = fmaf(bf2f((unsigned short)(x[j] >> 16)), w, a1);
    }
    p += 4;
  }
  if (p + 2 <= pe) {
    int2 e0 = entries[p], e1 = entries[p + 1];
    unsigned x0 = *(const unsigned*)(xin + ((size_t)e0.x << 6) + (l32 << 1));
    unsigned x1 = *(const unsigned*)(xin + ((size_t)e1.x << 6) + (l32 << 1));
    float w0 = __int_as_float(e0.y), w1 = __int_as_float(e1.y);
    a0 = fmaf(bf2f((unsigned short)(x0 & 0xffffu)), w0, a0);
    a1 = fmaf(bf2f((unsigned short)(x0 >> 16)), w0, a1);
    a0 = fmaf(bf2f((unsigned short)(x1 & 0xffffu)), w1, a0);
    a1 = fmaf(bf2f((unsigned short)(x1 >> 16)), w1, a1);
    p += 2;
  }
  if (p < pe) {
    int2 e = entries[p];
    unsigned x = *(const unsigned*)(xin + ((size_t)e.x << 6) + (l32 << 1));
    float w = __int_as_float(e.y);
    a0 = fmaf(bf2f((unsigned short)(x & 0xffffu)), w, a0);
    a1 = fmaf(bf2f((unsigned short)(x >> 16)), w, a1);
  }
  ra0 = a0; ra1 = a1;
}

// layer-1 aggregation: half-wave per node, ushort2 out (permuted pos layout)
__global__ void k_agg(const unsigned short* __restrict__ xin, const int2* __restrict__ entries,
                      const int* __restrict__ offs, const float* __restrict__ dis,
                      const float* __restrict__ bias, unsigned short* __restrict__ xout, int N) {
  const int tid = threadIdx.x;
  const int l32 = tid & 31;
  int i = blockIdx.x * 8 + (tid >> 5);
  if (i >= N) return;
  float a0, a1;
  row_gather2(xin, entries, offs[i], offs[i + 1], l32, a0, a1);
  float d = dis[i];
  a0 = fmaf(a0, d, bias[permcol(2 * l32)]);
  a1 = fmaf(a1, d, bias[permcol(2 * l32 + 1)]);
  a0 = fmaxf(a0, 0.f);
  a1 = fmaxf(a1, 0.f);
  ushort2 pk;
  pk.x = f2bf(a0);
  pk.y = f2bf(a1);
  *(ushort2*)(xout + ((size_t)i << 6) + (l32 << 1)) = pk;
}

// masked layer-2 aggregation: half-wave per masked node, fp32 out + y[mask]
__global__ void k_agg2m(const unsigned short* __restrict__ xin, const int2* __restrict__ entries,
                        const int* __restrict__ offs, const float* __restrict__ dis,
                        const int* __restrict__ mask, const int* __restrict__ y,
                        float* __restrict__ tout, float* __restrict__ outY, int M) {
  const int tid = threadIdx.x;
  const int l32 = tid & 31;
  int o = blockIdx.x * 8 + (tid >> 5);
  if (o >= M) return;
  int i = mask[o];
  float a0, a1;
  row_gather2(xin, entries, offs[i], offs[i + 1], l32, a0, a1);
  float d = dis[i];
  float2 pk;
  pk.x = a0 * d;
  pk.y = a1 * d;
  *(float2*)(tout + ((size_t)o << 6) + (l32 << 1)) = pk;
  if (l32 == 0) outY[o] = (float)y[i];
}

// final projection [M,64]@[64,64]+b2 via MFMA (permuted-k packed W2), fp32 out
__global__ __launch_bounds__(256) void k_mfma_final(
    const float* __restrict__ X, const unsigned short* __restrict__ packW2,
    const float* __restrict__ b2, float* __restrict__ out, int M) {
  mfma_gemm_body<false, true, 2, false>(X, 64, nullptr, packW2, nullptr, 2, 64,
                                        b2, out, M, blockIdx.x * 4 + (threadIdx.x >> 6),
                                        nullptr);
}

extern "C" void kernel_launch(void* const* d_in, const int* in_sizes, int n_in,
                              void* d_out, int out_size, void* d_ws, size_t ws_size,
                              hipStream_t stream) {
  const float* doc   = (const float*)d_in[0];
  const float* wordf = (const float*)d_in[1];
  const float* ew    = (const float*)d_in[2];
  const float* Wlin  = (const float*)d_in[3];
  const float* blin  = (const float*)d_in[4];
  const float* W1    = (const float*)d_in[5];
  const float* b1    = (const float*)d_in[6];
  const float* W2    = (const float*)d_in[7];
  const float* b2    = (const float*)d_in[8];
  const int*   ei    = (const int*)d_in[9];
  const int*   mask  = (const int*)d_in[10];
  const int*   y     = (const int*)d_in[11];

  const int E  = in_sizes[2];
  const int M  = in_sizes[10];
  const int ND = in_sizes[0] / 768;
  const int NW = in_sizes[1] / 300;
  const int N  = ND + NW;
  const int NE = N + E;

  // workspace carve (aligned 256B)
  char* p = (char*)d_ws;
  auto carve = [&](size_t bytes) -> void* {
    void* q = (void*)p;
    p += (bytes + 255) & ~(size_t)255;
    return q;
  };
  float*          WfuseB = (float*)carve(301 * 64 * 4);
  unsigned short* packW1 = (unsigned short*)carve((size_t)4 * 24 * 64 * 8 * 2);
  unsigned short* packW2 = (unsigned short*)carve((size_t)4 * 2 * 64 * 8 * 2);
  float* dis    = (float*)carve((size_t)N * 4);
  // cnt and packWf contiguous -> single memset covers both
  int*            cnt    = (int*)carve((size_t)N * 4);
  unsigned short* packWf = (unsigned short*)carve((size_t)4 * 10 * 64 * 8 * 2);
  int*   offs   = (int*)carve(((size_t)N + 1) * 4);
  int*   cursor = (int*)carve((size_t)N * 4);
  int*   bsum   = (int*)carve(1024);
  int2*  entries = (int2*)carve((size_t)NE * 8);
  unsigned short* xw1 = (unsigned short*)carve((size_t)N * 64 * 2);  // bf16, permuted cols
  unsigned short* h1  = (unsigned short*)carve((size_t)N * 64 * 2);  // bf16, permuted cols
  float* tmask = (float*)carve((size_t)M * 64 * 4);                  // fp32, permuted cols

  size_t zeroBytes = (size_t)((char*)packWf - (char*)cnt) + (size_t)4 * 10 * 64 * 8 * 2;
  hipMemsetAsync(cnt, 0, zeroBytes, stream);

  // k_pre: fuse MFMA (emits packWf) || pack W1 || pack W2 || cnt histogram
  const int fuseBlocks = (301 + 127) / 128;
  const int cntBlocks  = (E + 1023) / 1024;
  k_pre<<<fuseBlocks + 24 + 2 + cntBlocks, 256, 0, stream>>>(
      Wlin, blin, W1, WfuseB, packWf, packW1, W2, packW2, ei, E, cnt, fuseBlocks);

  // k_main: LDS-staged doc + word GEMMs
  const int docBlocks  = (ND + 63) / 64;
  const int wordBlocks = (NW + 63) / 64;
  k_main<<<docBlocks + wordBlocks, 256, 0, stream>>>(
      doc, packW1, xw1, ND, docBlocks,
      wordf, packWf, WfuseB + (size_t)300 * 64, xw1 + (size_t)ND * 64, NW);

  int nb = (N + 1023) / 1024;
  k_scan_reduce<<<nb, 256, 0, stream>>>(cnt, N, bsum);
  k_scan_final<<<nb, 256, 0, stream>>>(cnt, N, bsum, nb, offs, cursor, entries);

  k_fill<<<(E + 1023) / 1024, 256, 0, stream>>>(ei, ew, E, cursor, entries);

  k_degdis<<<(N + 255) / 256, 256, 0, stream>>>(entries, offs, dis, N);
  k_prenorm<<<(NE + 255) / 256, 256, 0, stream>>>(entries, dis, NE);

  // layer-1 aggregation (+b1 via pi, relu) -> bf16 h1 (permuted)
  k_agg<<<(N + 7) / 8, 256, 0, stream>>>(xw1, entries, offs, dis, b1, h1, N);

  // layer-2: masked aggregation over h1, then project [M,64]@[64,64]+b2
  float* out0 = (float*)d_out;
  float* outY = out0 + (size_t)M * 64;
  k_agg2m<<<(M + 7) / 8, 256, 0, stream>>>(h1, entries, offs, dis, mask, y, tmask, outY, M);
  k_mfma_final<<<(M + 127) / 128, 256, 0, stream>>>(tmask, packW2, b2, out0, M);
}